// Round 5
// baseline (271.740 us; speedup 1.0000x reference)
//
#include <hip/hip_runtime.h>
#include <hip/hip_bf16.h>

#define EE 400000
#define NN 50000
#define SCAN_NBLK ((NN + 1023) / 1024)
#define NTILES (EE / 16)      // 25000
#define NXCD 8
#define TPX (NTILES / NXCD)   // 3125

typedef float f32x4 __attribute__((ext_vector_type(4)));
typedef __bf16 bf16x8 __attribute__((ext_vector_type(8)));
typedef unsigned int u32;

static __device__ __forceinline__ bf16x8 u4_as_bf8(uint4 u) {
  return __builtin_bit_cast(bf16x8, u);
}
// relu on two packed bf16 in a dword (zero where sign bit set)
static __device__ __forceinline__ u32 relu_pk2(u32 d) {
  u32 m = (d & 0x80008000u) >> 15;  // 1 where negative
  m ^= 0x00010001u;                 // 1 where keep
  return d & ((m << 16) - m);       // expand to 16-bit masks
}
static __device__ __forceinline__ u32 pk2bf(float a, float b) {
  union { __bf16 h[2]; u32 w; } t;
  t.h[0] = (__bf16)a; t.h[1] = (__bf16)b;
  return t.w;
}

// ---------------- init: zero deg + fold head weights ----------------
__global__ void init_kernel(int* __restrict__ deg,
                            const float* __restrict__ wl01, const float* __restrict__ bl01,
                            const float* __restrict__ wl02, const float* __restrict__ bl02,
                            const float* __restrict__ wl1,  const float* __restrict__ bl1,
                            const float* __restrict__ wl2,  const float* __restrict__ bl2,
                            float* __restrict__ headw) {
  int i = blockIdx.x * blockDim.x + threadIdx.x;
  if (i < NN) deg[i] = 0;
  if (blockIdx.x == 0) {
    int t = threadIdx.x;
    if (t < 128) {                    // W_ex[k][c] = sum_j wl01[k][j]*wl1[j][c]
      int k = t >> 2, c = t & 3;
      float s = 0.f;
      for (int j = 0; j < 32; ++j) s += wl01[k*32 + j] * wl1[j*4 + c];
      headw[k*4 + c] = s;
    } else if (t < 160) {             // w_p[k] = sum_j wl02[k][j]*wl2[j]
      int k = t - 128;
      float s = 0.f;
      for (int j = 0; j < 32; ++j) s += wl02[k*32 + j] * wl2[j];
      headw[128 + k] = s;
    } else if (t < 164) {             // b_ex[c] = bl01@wl1 + bl1
      int c = t - 160;
      float s = bl1[c];
      for (int j = 0; j < 32; ++j) s += bl01[j] * wl1[j*4 + c];
      headw[160 + c] = s;
    } else if (t == 164) {            // b_p = bl02@wl2 + bl2
      float s = bl2[0];
      for (int j = 0; j < 32; ++j) s += bl02[j] * wl2[j];
      headw[164] = s;
    }
  }
}

// ---------------- pack weights into lane-ordered MFMA B fragments ----------
template <int STAGE>
__global__ void pack_kernel(const float* __restrict__ W0, const float* __restrict__ W1,
                            const float* __restrict__ headw, __bf16* __restrict__ pk) {
  constexpr int NKB = (STAGE == 1) ? 1 : (STAGE == 2) ? 4 : 6;
  const int f = blockIdx.x;
  const int t = threadIdx.x;
#pragma unroll
  for (int u = 0; u < 2; ++u) {
    int idx = t * 2 + u;              // 0..511
    int lane = idx >> 3;
    int i = idx & 7;
    int l15 = lane & 15, g = lane >> 4;
    float v;
    if (f < 2 * NKB) {
      int kb = f >> 1, nb = f & 1;
      int k = kb * 32 + 8 * g + i;
      int n = nb * 16 + l15;
      if (STAGE == 1)      v = (k < 4) ? W0[k * 32 + n] : 0.f;
      else if (STAGE == 2) v = (k < 68) ? W0[k * 32 + n] : ((k < 96) ? 0.f : W0[(k - 28) * 32 + n]);
      else                 v = W0[k * 32 + n];
    } else if (f < 2 * NKB + 2) {
      int nb = f - 2 * NKB;
      v = W1[(8 * g + i) * 32 + nb * 16 + l15];
    } else {
      int k = 8 * g + i;
      v = (l15 < 4) ? headw[k * 4 + l15] : ((l15 == 4) ? headw[128 + k] : 0.f);
    }
    pk[f * 512 + idx] = (__bf16)v;
  }
}

// ---------------- CSR build ----------------
__global__ void hist_kernel(const int* __restrict__ rowi, int* __restrict__ deg) {
  int e = blockIdx.x * blockDim.x + threadIdx.x;
  if (e < EE) atomicAdd(&deg[rowi[e]], 1);
}

__global__ void scanA_kernel(const int* __restrict__ deg, int* __restrict__ offs,
                             int* __restrict__ partial) {
  __shared__ int lds[1024];
  const int t = threadIdx.x;
  const int i = blockIdx.x * 1024 + t;
  int v = (i < NN) ? deg[i] : 0;
  lds[t] = v;
  __syncthreads();
  for (int off = 1; off < 1024; off <<= 1) {
    int u = (t >= off) ? lds[t - off] : 0;
    __syncthreads();
    lds[t] += u;
    __syncthreads();
  }
  int incl = lds[t];
  if (i < NN) offs[i] = incl - v;     // local exclusive prefix
  if (t == 1023) partial[blockIdx.x] = incl;
}

__global__ void scanB_kernel(const int* __restrict__ partial, int* __restrict__ offs,
                             int* __restrict__ cursor) {
  __shared__ int sbase;
  const int t = threadIdx.x;
  const int b = blockIdx.x;
  if (t < 64) {
    int s = (t < b && t < SCAN_NBLK) ? partial[t] : 0;
#pragma unroll
    for (int o = 32; o > 0; o >>= 1) s += __shfl_down(s, o);
    if (t == 0) sbase = s;
  }
  __syncthreads();
  const int base = sbase;
  const int i = b * 1024 + t;
  if (i < NN) {
    int o = offs[i] + base;
    offs[i] = o;
    cursor[i] = o;
  }
  if (b == 0 && t == 0) offs[NN] = EE;  // total is EE by construction
}

__global__ void scatter_kernel(const int* __restrict__ rowi, int* __restrict__ cursor,
                               int* __restrict__ csr) {
  int e = blockIdx.x * blockDim.x + threadIdx.x;
  if (e < EE) { int p = atomicAdd(&cursor[rowi[e]], 1); csr[p] = e; }
}

// ---------------- permute edge meta into sorted (CSR) order + inverse -------
__global__ void permute_kernel(const int* __restrict__ csr,
                               const int* __restrict__ rowi, const int* __restrict__ coli,
                               const float* __restrict__ eattr,
                               int* __restrict__ rows_s, int* __restrict__ cols_s,
                               __bf16* __restrict__ ebf, float* __restrict__ eattr_s,
                               int* __restrict__ inv) {
  int p = blockIdx.x * blockDim.x + threadIdx.x;
  if (p >= EE) return;
  int e = csr[p];
  inv[e] = p;
  rows_s[p] = rowi[e];
  cols_s[p] = coli[e];
  const float4 v = *(const float4*)(eattr + (size_t)e * 4);
  *(float4*)(eattr_s + (size_t)p * 4) = v;
  u32 lo = pk2bf(v.x, v.y), hi = pk2bf(v.z, v.w);
  *(uint2*)(ebf + (size_t)p * 4) = make_uint2(lo, hi);
}

// ---------------- segment mean: edges are CONTIGUOUS rows [offs[n], offs[n+1])
__global__ void agg_kernel(const __bf16* __restrict__ esrc,
                           const int* __restrict__ offs,
                           __bf16* __restrict__ dst1, int s1, int o1,
                           __bf16* __restrict__ dst2, int s2, int o2) {
  int idx = blockIdx.x * blockDim.x + threadIdx.x;
  int n = idx >> 5;
  int j = idx & 31;
  if (n >= NN) return;
  int a = offs[n], b = offs[n + 1];
  float s = 0.f;
  for (int t = a; t < b; ++t)
    s += (float)esrc[(size_t)t * 32 + j];
  float mean = s / fmaxf((float)(b - a), 1.f);
  __bf16 x = (__bf16)fmaxf(mean, 0.f);
  dst1[(size_t)n * s1 + o1 + j] = x;
  if (dst2) dst2[(size_t)n * s2 + o2 + j] = x;
}

// ---------------- fused edge-conv (MFMA), sorted edge order, XCD-chunked ----
// STAGE1: e1 = mlp(ea)                          -> e1b
// STAGE2: e2 = mlp(x1[r]|x1[c]|ea|e1)           -> e2b
// STAGE3: e3 = mlp(x21[r]|x21[c]|e2|e1)         -> e3b
// STAGE4: e4 = relu(mlp(x32[r]|x32[c]|e3|e2)); heads -> tmpP/tmpEX (dense)
template <int STAGE>
__launch_bounds__(256, 6)
__global__ void conv_kernel(const __bf16* __restrict__ packw,
                            const float* __restrict__ B0, const float* __restrict__ B1v,
                            const int* __restrict__ rows_s, const int* __restrict__ cols_s,
                            const __bf16* __restrict__ ebf,
                            const __bf16* __restrict__ nodebuf,
                            const __bf16* __restrict__ ein1,
                            const __bf16* __restrict__ ein2,
                            __bf16* __restrict__ d1,
                            const float* __restrict__ eattr_s,
                            const float* __restrict__ headw,
                            float* __restrict__ tmpP, float* __restrict__ tmpEX) {
  constexpr int NKB = (STAGE == 1) ? 1 : (STAGE == 2) ? 4 : 6;
  __shared__ __align__(16) float ldsH[4 * 16 * 36];

  const int tid = threadIdx.x;
  const int lane = tid & 63;
  const int wid = tid >> 6;
  const int l15 = lane & 15;
  const int g = lane >> 4;

  // B fragments: coalesced 16B loads from pre-packed buffer
  bf16x8 Bf[NKB][2];
#pragma unroll
  for (int kb = 0; kb < NKB; ++kb)
#pragma unroll
    for (int nb = 0; nb < 2; ++nb)
      Bf[kb][nb] = *(const bf16x8*)(packw + (size_t)(kb * 2 + nb) * 512 + lane * 8);
  bf16x8 B2f[2];
#pragma unroll
  for (int nb = 0; nb < 2; ++nb)
    B2f[nb] = *(const bf16x8*)(packw + (size_t)(2 * NKB + nb) * 512 + lane * 8);
  const float b0j0 = B0[l15], b0j1 = B0[l15 + 16];
  const float b1j0 = B1v[l15], b1j1 = B1v[l15 + 16];

  bf16x8 Bh;
  float bexc = 0.f, bp = 0.f;
  if (STAGE == 4) {
    Bh = *(const bf16x8*)(packw + (size_t)(2 * NKB + 2) * 512 + lane * 8);
    if (l15 < 4) bexc = headw[160 + l15];
    bp = headw[164];
  }

  float* hl = &ldsH[wid * 576];

  // XCD-chunked walk: xcd = blockIdx&7 owns sorted-tile chunk [xcd*TPX, (xcd+1)*TPX)
  const int xcd = blockIdx.x & 7;
  const int wloc = (blockIdx.x >> 3) * 4 + wid;
  const int nwl = (gridDim.x >> 3) * 4;
  for (int t0 = wloc; t0 < TPX; t0 += nwl) {
    const int t = xcd * TPX + t0;
    const int base = t * 16;
    const int p = base + l15;         // sorted position
    int rid = 0, cid = 0;
    if (STAGE >= 2) { rid = rows_s[p]; cid = cols_s[p]; }

    bf16x8 ae;
    if (STAGE <= 2) {
      uint4 u = {0, 0, 0, 0};
      if (g == 0) {
        const uint2 v = *(const uint2*)(ebf + (size_t)p * 4);
        u.x = v.x; u.y = v.y;
      }
      ae = u4_as_bf8(u);
    }

    f32x4 acc0 = {0, 0, 0, 0}, acc1 = {0, 0, 0, 0};
#pragma unroll
    for (int kb = 0; kb < NKB; ++kb) {
      bf16x8 a;
      if (STAGE == 1) {
        a = ae;
      } else if (STAGE == 2) {
        if (kb == 0)      a = u4_as_bf8(*(const uint4*)(nodebuf + (size_t)rid * 32 + 8 * g));
        else if (kb == 1) a = u4_as_bf8(*(const uint4*)(nodebuf + (size_t)cid * 32 + 8 * g));
        else if (kb == 2) a = ae;
        else {
          uint4 u = *(const uint4*)(ein1 + (size_t)p * 32 + 8 * g);
          u.x = relu_pk2(u.x); u.y = relu_pk2(u.y); u.z = relu_pk2(u.z); u.w = relu_pk2(u.w);
          a = u4_as_bf8(u);
        }
      } else {
        if (kb < 2)      a = u4_as_bf8(*(const uint4*)(nodebuf + (size_t)rid * 64 + kb * 32 + 8 * g));
        else if (kb < 4) a = u4_as_bf8(*(const uint4*)(nodebuf + (size_t)cid * 64 + (kb - 2) * 32 + 8 * g));
        else {
          const __bf16* src = (kb == 4) ? ein1 : ein2;
          uint4 u = *(const uint4*)(src + (size_t)p * 32 + 8 * g);
          u.x = relu_pk2(u.x); u.y = relu_pk2(u.y); u.z = relu_pk2(u.z); u.w = relu_pk2(u.w);
          a = u4_as_bf8(u);
        }
      }
      acc0 = __builtin_amdgcn_mfma_f32_16x16x32_bf16(a, Bf[kb][0], acc0, 0, 0, 0);
      acc1 = __builtin_amdgcn_mfma_f32_16x16x32_bf16(a, Bf[kb][1], acc1, 0, 0, 0);
    }

    // h = relu(acc + b0) -> per-wave LDS tile [16][36]
#pragma unroll
    for (int r = 0; r < 4; ++r) {
      int m = 4 * g + r;
      hl[m * 36 + l15]      = fmaxf(acc0[r] + b0j0, 0.f);
      hl[m * 36 + l15 + 16] = fmaxf(acc1[r] + b0j1, 0.f);
    }
    // layer-2 A fragment (same-wave LDS round-trip; compiler orders ds ops)
    f32x4 h0 = *(const f32x4*)&hl[l15 * 36 + 8 * g];
    f32x4 h1 = *(const f32x4*)&hl[l15 * 36 + 8 * g + 4];
    bf16x8 a2;
#pragma unroll
    for (int i = 0; i < 4; ++i) { a2[i] = (__bf16)h0[i]; a2[i + 4] = (__bf16)h1[i]; }
    f32x4 o0 = {0, 0, 0, 0}, o1 = {0, 0, 0, 0};
    o0 = __builtin_amdgcn_mfma_f32_16x16x32_bf16(a2, B2f[0], o0, 0, 0, 0);
    o1 = __builtin_amdgcn_mfma_f32_16x16x32_bf16(a2, B2f[1], o1, 0, 0, 0);

    if (STAGE <= 3) {
#pragma unroll
      for (int r = 0; r < 4; ++r) {
        int m = 4 * g + r;
        size_t eo = (size_t)(base + m) * 32;
        d1[eo + l15]      = (__bf16)(o0[r] + b1j0);
        d1[eo + l15 + 16] = (__bf16)(o1[r] + b1j1);
      }
    } else {
      // e4 = relu -> LDS -> heads MFMA (B = [W_ex | w_p | 0])
#pragma unroll
      for (int r = 0; r < 4; ++r) {
        int m = 4 * g + r;
        hl[m * 36 + l15]      = fmaxf(o0[r] + b1j0, 0.f);
        hl[m * 36 + l15 + 16] = fmaxf(o1[r] + b1j1, 0.f);
      }
      f32x4 q0 = *(const f32x4*)&hl[l15 * 36 + 8 * g];
      f32x4 q1 = *(const f32x4*)&hl[l15 * 36 + 8 * g + 4];
      bf16x8 a3;
#pragma unroll
      for (int i = 0; i < 4; ++i) { a3[i] = (__bf16)q0[i]; a3[i + 4] = (__bf16)q1[i]; }
      f32x4 ho = {0, 0, 0, 0};
      ho = __builtin_amdgcn_mfma_f32_16x16x32_bf16(a3, Bh, ho, 0, 0, 0);
#pragma unroll
      for (int r = 0; r < 4; ++r) {
        int m = 4 * g + r;
        int po = base + m;            // DENSE sorted-position writes
        float s = ho[r];
        float v = 0.f, sq = 0.f;
        if (l15 < 4) {
          v = s + bexc + eattr_s[(size_t)po * 4 + l15];
          sq = v * v;
        }
        sq += __shfl_xor(sq, 1);
        sq += __shfl_xor(sq, 2);
        if (l15 < 4) tmpEX[(size_t)po * 4 + l15] = v * (1.f / fmaxf(sqrtf(sq), 1e-12f));
        if (l15 == 4) tmpP[po] = 1.f / (1.f + __expf(-(s + bp)));
      }
    }
  }
}

// ---------------- unpermute: dense writes in original edge order ----------
__global__ void unpermute_kernel(const int* __restrict__ inv,
                                 const float* __restrict__ tmpP,
                                 const float* __restrict__ tmpEX,
                                 float* __restrict__ outP, float* __restrict__ outEX) {
  int e = blockIdx.x * blockDim.x + threadIdx.x;
  if (e >= EE) return;
  int p = inv[e];
  outP[e] = tmpP[p];
  float4 ex = *(const float4*)(tmpEX + (size_t)p * 4);
  *(float4*)(outEX + (size_t)e * 4) = ex;
}

__global__ void beta_kernel(const float* __restrict__ beta, float* __restrict__ out) {
  int i = blockIdx.x * blockDim.x + threadIdx.x;
  if (i < NN * 3) out[i] = beta[i];
}

extern "C" void kernel_launch(void* const* d_in, const int* in_sizes, int n_in,
                              void* d_out, int out_size, void* d_ws, size_t ws_size,
                              hipStream_t stream) {
  const float* eattr = (const float*)d_in[2];
  const float* beta = (const float*)d_in[3];
  const float* w10 = (const float*)d_in[4];  const float* b10 = (const float*)d_in[5];
  const float* w11 = (const float*)d_in[6];  const float* b11 = (const float*)d_in[7];
  const float* w20 = (const float*)d_in[8];  const float* b20 = (const float*)d_in[9];
  const float* w21 = (const float*)d_in[10]; const float* b21 = (const float*)d_in[11];
  const float* w30 = (const float*)d_in[12]; const float* b30 = (const float*)d_in[13];
  const float* w31 = (const float*)d_in[14]; const float* b31 = (const float*)d_in[15];
  const float* w40 = (const float*)d_in[16]; const float* b40 = (const float*)d_in[17];
  const float* w41 = (const float*)d_in[18]; const float* b41 = (const float*)d_in[19];
  const float* wl01 = (const float*)d_in[20]; const float* bl01 = (const float*)d_in[21];
  const float* wl02 = (const float*)d_in[22]; const float* bl02 = (const float*)d_in[23];
  const float* wl1 = (const float*)d_in[24];  const float* bl1 = (const float*)d_in[25];
  const float* wl2 = (const float*)d_in[26];  const float* bl2 = (const float*)d_in[27];
  const int* rowi = (const int*)d_in[1];
  const int* coli = rowi + EE;

  char* w = (char*)d_ws;
  auto alloc = [&](size_t bytes) {
    char* p = w;
    w += (bytes + 255) & ~(size_t)255;
    return p;
  };
  __bf16* e1b = (__bf16*)alloc((size_t)EE * 32 * 2);  // pre-relu, sorted order
  __bf16* e2b = (__bf16*)alloc((size_t)EE * 32 * 2);
  __bf16* e3b = (__bf16*)alloc((size_t)EE * 32 * 2);
  __bf16* x1b = (__bf16*)alloc((size_t)NN * 32 * 2);
  __bf16* x21 = (__bf16*)alloc((size_t)NN * 64 * 2);  // [x2 | x1]
  __bf16* x32 = (__bf16*)alloc((size_t)NN * 64 * 2);  // [x3 | x2]
  int* deg = (int*)alloc(NN * 4);
  int* offs = (int*)alloc((NN + 1) * 4);
  int* cursor = (int*)alloc(NN * 4);
  int* csr = (int*)alloc(EE * 4);
  int* rows_s = (int*)alloc(EE * 4);
  int* cols_s = (int*)alloc(EE * 4);
  int* inv = (int*)alloc(EE * 4);
  __bf16* ebf = (__bf16*)alloc((size_t)EE * 4 * 2);   // sorted bf16 edge_attr
  float* eattr_s = (float*)alloc((size_t)EE * 4 * 4); // sorted fp32 edge_attr
  float* tmpP = (float*)alloc((size_t)EE * 4);        // sorted dense outputs
  float* tmpEX = (float*)alloc((size_t)EE * 4 * 4);
  float* headw = (float*)alloc(256 * 4);
  int* partial = (int*)alloc(64 * 4);
  __bf16* packw = (__bf16*)alloc(22016 * 2);          // packed fragments, all stages

  float* outP = (float*)d_out;
  float* outEX = outP + EE;
  float* outB = outP + (size_t)5 * EE;

  init_kernel<<<(NN + 255) / 256, 256, 0, stream>>>(deg, wl01, bl01, wl02, bl02, wl1, bl1, wl2, bl2, headw);
  hist_kernel<<<(EE + 255) / 256, 256, 0, stream>>>(rowi, deg);
  scanA_kernel<<<SCAN_NBLK, 1024, 0, stream>>>(deg, offs, partial);
  scanB_kernel<<<SCAN_NBLK, 1024, 0, stream>>>(partial, offs, cursor);
  scatter_kernel<<<(EE + 255) / 256, 256, 0, stream>>>(rowi, cursor, csr);
  permute_kernel<<<(EE + 255) / 256, 256, 0, stream>>>(csr, rowi, coli, eattr,
                                                       rows_s, cols_s, ebf, eattr_s, inv);

  __bf16* pk1 = packw;
  __bf16* pk2 = packw + 2048;
  __bf16* pk3 = packw + 7168;
  __bf16* pk4 = packw + 14336;
  pack_kernel<1><<<4, 256, 0, stream>>>(w10, w11, (const float*)nullptr, pk1);
  pack_kernel<2><<<10, 256, 0, stream>>>(w20, w21, (const float*)nullptr, pk2);
  pack_kernel<3><<<14, 256, 0, stream>>>(w30, w31, (const float*)nullptr, pk3);
  pack_kernel<4><<<15, 256, 0, stream>>>(w40, w41, headw, pk4);  // after init (headw)

  conv_kernel<1><<<2048, 256, 0, stream>>>(pk1, b10, b11, rows_s, cols_s, ebf,
                                           (const __bf16*)nullptr, (const __bf16*)nullptr,
                                           (const __bf16*)nullptr, e1b,
                                           (const float*)nullptr, (const float*)nullptr,
                                           (float*)nullptr, (float*)nullptr);
  agg_kernel<<<(NN * 32 + 255) / 256, 256, 0, stream>>>(e1b, offs, x1b, 32, 0, x21, 64, 32);
  conv_kernel<2><<<2048, 256, 0, stream>>>(pk2, b20, b21, rows_s, cols_s, ebf,
                                           x1b, e1b, (const __bf16*)nullptr, e2b,
                                           (const float*)nullptr, (const float*)nullptr,
                                           (float*)nullptr, (float*)nullptr);
  agg_kernel<<<(NN * 32 + 255) / 256, 256, 0, stream>>>(e2b, offs, x21, 64, 0, x32, 64, 32);
  conv_kernel<3><<<2048, 256, 0, stream>>>(pk3, b30, b31, rows_s, cols_s, ebf,
                                           x21, e2b, e1b, e3b,
                                           (const float*)nullptr, (const float*)nullptr,
                                           (float*)nullptr, (float*)nullptr);
  agg_kernel<<<(NN * 32 + 255) / 256, 256, 0, stream>>>(e3b, offs, x32, 64, 0, (__bf16*)nullptr, 0, 0);
  conv_kernel<4><<<2048, 256, 0, stream>>>(pk4, b40, b41, rows_s, cols_s, ebf,
                                           x32, e3b, e2b, (__bf16*)nullptr,
                                           eattr_s, headw, tmpP, tmpEX);
  unpermute_kernel<<<(EE + 255) / 256, 256, 0, stream>>>(inv, tmpP, tmpEX, outP, outEX);
  beta_kernel<<<(NN * 3 + 255) / 256, 256, 0, stream>>>(beta, outB);
}

// Round 6
// 227.987 us; speedup vs baseline: 1.1919x; 1.1919x over previous
//
#include <hip/hip_runtime.h>
#include <hip/hip_bf16.h>

#define EE 400000
#define NN 50000
#define SCAN_NBLK ((NN + 1023) / 1024)
#define NTILES (EE / 16)      // 25000
#define TPX (NTILES / 8)      // 3125 tiles per XCD chunk
#define NPTILES ((NN + 15) / 16)

typedef float f32x4 __attribute__((ext_vector_type(4)));
typedef __bf16 bf16x8 __attribute__((ext_vector_type(8)));
typedef unsigned int u32;

static __device__ __forceinline__ bf16x8 u4_as_bf8(uint4 u) {
  return __builtin_bit_cast(bf16x8, u);
}
static __device__ __forceinline__ u32 relu_pk2(u32 d) {
  u32 m = (d & 0x80008000u) >> 15;
  m ^= 0x00010001u;
  return d & ((m << 16) - m);
}
static __device__ __forceinline__ u32 pk2bf(float a, float b) {
  union { __bf16 h[2]; u32 w; } t;
  t.h[0] = (__bf16)a; t.h[1] = (__bf16)b;
  return t.w;
}

// ---------------- init: zero deg + head bias scalars ----------------
__global__ void init_kernel(int* __restrict__ deg,
                            const float* __restrict__ bl01, const float* __restrict__ bl02,
                            const float* __restrict__ wl1,  const float* __restrict__ bl1,
                            const float* __restrict__ wl2,  const float* __restrict__ bl2,
                            float* __restrict__ headw) {
  int i = blockIdx.x * blockDim.x + threadIdx.x;
  if (i < NN) deg[i] = 0;
  if (blockIdx.x == 0) {
    int t = threadIdx.x;
    if (t < 4) {                      // b_ex[c] = bl01@wl1 + bl1
      float s = bl1[t];
      for (int j = 0; j < 32; ++j) s += bl01[j] * wl1[j * 4 + t];
      headw[160 + t] = s;
    } else if (t == 4) {              // b_p = bl02@wl2 + bl2
      float s = bl2[0];
      for (int j = 0; j < 32; ++j) s += bl02[j] * wl2[j];
      headw[164] = s;
    }
  }
}

// ---------------- pack ALL stages' MFMA B fragments (one launch) -----------
// stage frag layout (local lf):
// S1 (f 0..3):   lf0,1 = W0 (rows k<4) halves; lf2,3 = W1 halves
// S2 (f 4..13):  lf0..3 = nodeproj B (part r/c, nb), rows part*32+k
//                lf4,5 = ea block (rows 64+k, k<4); lf6,7 = e1 block (rows 68+k)
//                lf8,9 = W1
// S3 (f14..27):  lf0..7 = nodeproj B (part*64 + kb*32 + k); lf8..11 = edge blocks
//                (rows 128 + eb*32 + k); lf12,13 = W1
// S4 (f28..42):  same as S3 + lf14 = head frag [W_ex | w_p | 0]
__global__ void pack_all_kernel(const float* __restrict__ w10, const float* __restrict__ w11,
                                const float* __restrict__ w20, const float* __restrict__ w21,
                                const float* __restrict__ w30, const float* __restrict__ w31,
                                const float* __restrict__ w40, const float* __restrict__ w41,
                                const float* __restrict__ wl01, const float* __restrict__ wl1,
                                const float* __restrict__ wl02, const float* __restrict__ wl2,
                                __bf16* __restrict__ pk) {
  const int f = blockIdx.x;
  const int t = threadIdx.x;
  int stage, lf;
  const float *W0, *W1;
  if (f < 4)       { stage = 1; lf = f;      W0 = w10; W1 = w11; }
  else if (f < 14) { stage = 2; lf = f - 4;  W0 = w20; W1 = w21; }
  else if (f < 28) { stage = 3; lf = f - 14; W0 = w30; W1 = w31; }
  else             { stage = 4; lf = f - 28; W0 = w40; W1 = w41; }
#pragma unroll
  for (int u = 0; u < 2; ++u) {
    int idx = t * 2 + u;
    int lane = idx >> 3, i = idx & 7;
    int l15 = lane & 15, g = lane >> 4;
    int k = 8 * g + i;
    float v = 0.f;
    if (stage == 1) {
      if (lf < 2)      v = (k < 4) ? W0[k * 32 + lf * 16 + l15] : 0.f;
      else             v = W1[k * 32 + (lf - 2) * 16 + l15];
    } else if (stage == 2) {
      if (lf < 4)      { int part = lf >> 1, nb = lf & 1; v = W0[(part * 32 + k) * 32 + nb * 16 + l15]; }
      else if (lf < 6) { int nb = lf - 4; v = (k < 4) ? W0[(64 + k) * 32 + nb * 16 + l15] : 0.f; }
      else if (lf < 8) { int nb = lf - 6; v = W0[(68 + k) * 32 + nb * 16 + l15]; }
      else             { int nb = lf - 8; v = W1[k * 32 + nb * 16 + l15]; }
    } else {
      if (lf < 8)       { int part = lf >> 2, kb = (lf >> 1) & 1, nb = lf & 1;
                          v = W0[(part * 64 + kb * 32 + k) * 32 + nb * 16 + l15]; }
      else if (lf < 12) { int eb = (lf - 8) >> 1, nb = lf & 1;
                          v = W0[(128 + eb * 32 + k) * 32 + nb * 16 + l15]; }
      else if (lf < 14) { int nb = lf - 12; v = W1[k * 32 + nb * 16 + l15]; }
      else {              // head frag (stage 4 only)
        if (l15 < 4)      { float s = 0.f; for (int j = 0; j < 32; ++j) s += wl01[k * 32 + j] * wl1[j * 4 + l15]; v = s; }
        else if (l15 == 4){ float s = 0.f; for (int j = 0; j < 32; ++j) s += wl02[k * 32 + j] * wl2[j]; v = s; }
      }
    }
    pk[f * 512 + idx] = (__bf16)v;
  }
}

// ---------------- CSR build ----------------
__global__ void hist_kernel(const int* __restrict__ rowi, int* __restrict__ deg) {
  int e = blockIdx.x * blockDim.x + threadIdx.x;
  if (e < EE) atomicAdd(&deg[rowi[e]], 1);
}

__global__ void scanA_kernel(const int* __restrict__ deg, int* __restrict__ offs,
                             int* __restrict__ partial) {
  __shared__ int lds[1024];
  const int t = threadIdx.x;
  const int i = blockIdx.x * 1024 + t;
  int v = (i < NN) ? deg[i] : 0;
  lds[t] = v;
  __syncthreads();
  for (int off = 1; off < 1024; off <<= 1) {
    int u = (t >= off) ? lds[t - off] : 0;
    __syncthreads();
    lds[t] += u;
    __syncthreads();
  }
  int incl = lds[t];
  if (i < NN) offs[i] = incl - v;
  if (t == 1023) partial[blockIdx.x] = incl;
}

__global__ void scanB_kernel(const int* __restrict__ partial, int* __restrict__ offs,
                             int* __restrict__ cursor) {
  __shared__ int sbase;
  const int t = threadIdx.x;
  const int b = blockIdx.x;
  if (t < 64) {
    int s = (t < b && t < SCAN_NBLK) ? partial[t] : 0;
#pragma unroll
    for (int o = 32; o > 0; o >>= 1) s += __shfl_down(s, o);
    if (t == 0) sbase = s;
  }
  __syncthreads();
  const int base = sbase;
  const int i = b * 1024 + t;
  if (i < NN) {
    int o = offs[i] + base;
    offs[i] = o;
    cursor[i] = o;
  }
  if (b == 0 && t == 0) offs[NN] = EE;
}

// scatter + permute fused: place each edge's meta at its sorted position
__global__ void scatter_kernel(const int* __restrict__ rowi, const int* __restrict__ coli,
                               const float* __restrict__ eattr, int* __restrict__ cursor,
                               int* __restrict__ rows_s, int* __restrict__ cols_s,
                               __bf16* __restrict__ ebf, float* __restrict__ eattr_s,
                               int* __restrict__ inv) {
  int e = blockIdx.x * blockDim.x + threadIdx.x;
  if (e >= EE) return;
  int r = rowi[e];
  int p = atomicAdd(&cursor[r], 1);
  inv[e] = p;
  rows_s[p] = r;
  cols_s[p] = coli[e];
  const float4 v = *(const float4*)(eattr + (size_t)e * 4);
  *(float4*)(eattr_s + (size_t)p * 4) = v;
  *(uint2*)(ebf + (size_t)p * 4) = make_uint2(pk2bf(v.x, v.y), pk2bf(v.z, v.w));
}

// ---------------- segment mean: contiguous rows [offs[n], offs[n+1]) --------
__global__ void agg_kernel(const __bf16* __restrict__ esrc,
                           const int* __restrict__ offs,
                           __bf16* __restrict__ dst1, int s1, int o1,
                           __bf16* __restrict__ dst2, int s2, int o2) {
  int idx = blockIdx.x * blockDim.x + threadIdx.x;
  int n = idx >> 5;
  int j = idx & 31;
  if (n >= NN) return;
  int a = offs[n], b = offs[n + 1];
  float s = 0.f;
  for (int t = a; t < b; ++t)
    s += (float)esrc[(size_t)t * 32 + j];
  float mean = s / fmaxf((float)(b - a), 1.f);
  __bf16 x = (__bf16)fmaxf(mean, 0.f);
  dst1[(size_t)n * s1 + o1 + j] = x;
  if (dst2) dst2[(size_t)n * s2 + o2 + j] = x;
}

// ---------------- node projection: u[n] = [W_r . x[n] | W_c . x[n]] --------
// NPK = K of the node part (32 for stage2, 64 for stage3/4). pk = stage base.
template <int NPK>
__launch_bounds__(256, 4)
__global__ void nodeproj_kernel(const __bf16* __restrict__ pk,
                                const __bf16* __restrict__ xcat, int xoff, int xstride,
                                __bf16* __restrict__ ub) {
  constexpr int NKB = NPK / 32;
  const int tid = threadIdx.x;
  const int lane = tid & 63;
  const int wid = tid >> 6;
  const int l15 = lane & 15;
  const int g = lane >> 4;

  bf16x8 Br[NKB][2], Bc[NKB][2];
#pragma unroll
  for (int kb = 0; kb < NKB; ++kb)
#pragma unroll
    for (int nb = 0; nb < 2; ++nb) {
      Br[kb][nb] = *(const bf16x8*)(pk + (size_t)((0 * NKB + kb) * 2 + nb) * 512 + lane * 8);
      Bc[kb][nb] = *(const bf16x8*)(pk + (size_t)((1 * NKB + kb) * 2 + nb) * 512 + lane * 8);
    }

  const int t = blockIdx.x * 4 + wid;
  if (t >= NPTILES) return;
  const int base = t * 16;
  const int n = base + l15;
  const int nc = (n < NN) ? n : (NN - 1);   // clamp tail reads

  f32x4 r0 = {0,0,0,0}, r1 = {0,0,0,0}, c0 = {0,0,0,0}, c1 = {0,0,0,0};
#pragma unroll
  for (int kb = 0; kb < NKB; ++kb) {
    bf16x8 a = *(const bf16x8*)(xcat + (size_t)nc * xstride + xoff + kb * 32 + 8 * g);
    r0 = __builtin_amdgcn_mfma_f32_16x16x32_bf16(a, Br[kb][0], r0, 0, 0, 0);
    r1 = __builtin_amdgcn_mfma_f32_16x16x32_bf16(a, Br[kb][1], r1, 0, 0, 0);
    c0 = __builtin_amdgcn_mfma_f32_16x16x32_bf16(a, Bc[kb][0], c0, 0, 0, 0);
    c1 = __builtin_amdgcn_mfma_f32_16x16x32_bf16(a, Bc[kb][1], c1, 0, 0, 0);
  }
#pragma unroll
  for (int r = 0; r < 4; ++r) {
    int m = 4 * g + r;
    if (base + m < NN) {
      size_t row = (size_t)(base + m) * 64;
      ub[row + l15]      = (__bf16)r0[r];
      ub[row + 16 + l15] = (__bf16)r1[r];
      ub[row + 32 + l15] = (__bf16)c0[r];
      ub[row + 48 + l15] = (__bf16)c1[r];
    }
  }
}

// ---------------- fused edge-conv (MFMA), sorted order, XCD-chunked --------
// node parts injected via identity-MFMA from precomputed u tables.
template <int STAGE>
__launch_bounds__(256, 5)
__global__ void conv_kernel(const __bf16* __restrict__ pk,
                            const float* __restrict__ B0, const float* __restrict__ B1v,
                            const int* __restrict__ rows_s, const int* __restrict__ cols_s,
                            const __bf16* __restrict__ ebf,
                            const __bf16* __restrict__ ub,
                            const __bf16* __restrict__ ein1,
                            const __bf16* __restrict__ ein2,
                            __bf16* __restrict__ d1,
                            const float* __restrict__ eattr_s,
                            const float* __restrict__ headw,
                            float* __restrict__ tmpP, float* __restrict__ tmpEX) {
  constexpr int NEB  = (STAGE == 1) ? 1 : 2;
  constexpr int FEB  = (STAGE == 1) ? 0 : (STAGE == 2) ? 4 : 8;
  constexpr int FW1  = (STAGE == 1) ? 2 : (STAGE == 2) ? 8 : 12;
  __shared__ __align__(16) float ldsH[4 * 16 * 36];

  const int tid = threadIdx.x;
  const int lane = tid & 63;
  const int wid = tid >> 6;
  const int l15 = lane & 15;
  const int g = lane >> 4;

  bf16x8 Bf[NEB][2];
#pragma unroll
  for (int eb = 0; eb < NEB; ++eb)
#pragma unroll
    for (int nb = 0; nb < 2; ++nb)
      Bf[eb][nb] = *(const bf16x8*)(pk + (size_t)(FEB + eb * 2 + nb) * 512 + lane * 8);
  bf16x8 B2f[2];
#pragma unroll
  for (int nb = 0; nb < 2; ++nb)
    B2f[nb] = *(const bf16x8*)(pk + (size_t)(FW1 + nb) * 512 + lane * 8);

  // identity B fragments (registers only)
  bf16x8 I0, I1;
#pragma unroll
  for (int i = 0; i < 8; ++i) {
    int k = 8 * g + i;
    I0[i] = (k == l15)      ? (__bf16)1.0f : (__bf16)0.0f;
    I1[i] = (k == 16 + l15) ? (__bf16)1.0f : (__bf16)0.0f;
  }

  const float b0j0 = B0[l15], b0j1 = B0[l15 + 16];
  const float b1j0 = B1v[l15], b1j1 = B1v[l15 + 16];

  bf16x8 Bh;
  float bexc = 0.f, bp = 0.f;
  if (STAGE == 4) {
    Bh = *(const bf16x8*)(pk + (size_t)14 * 512 + lane * 8);
    if (l15 < 4) bexc = headw[160 + l15];
    bp = headw[164];
  }

  float* hl = &ldsH[wid * 576];

  const int xcd = blockIdx.x & 7;
  const int wloc = (blockIdx.x >> 3) * 4 + wid;
  const int nwl = (gridDim.x >> 3) * 4;
  for (int t0 = wloc; t0 < TPX; t0 += nwl) {
    const int t = xcd * TPX + t0;
    const int base = t * 16;
    const int p = base + l15;

    bf16x8 urf, ucf;
    if (STAGE >= 2) {
      int rid = rows_s[p], cid = cols_s[p];
      urf = *(const bf16x8*)(ub + (size_t)rid * 64 + 8 * g);
      ucf = *(const bf16x8*)(ub + (size_t)cid * 64 + 32 + 8 * g);
    }

    bf16x8 ae;
    if (STAGE <= 2) {
      uint4 u = {0, 0, 0, 0};
      if (g == 0) {
        const uint2 v = *(const uint2*)(ebf + (size_t)p * 4);
        u.x = v.x; u.y = v.y;
      }
      ae = u4_as_bf8(u);
    }

    // two independent accumulator chains per half, merged at the end
    f32x4 a0a = {0,0,0,0}, a0b = {0,0,0,0}, a1a = {0,0,0,0}, a1b = {0,0,0,0};
    if (STAGE >= 2) {
      a0a = __builtin_amdgcn_mfma_f32_16x16x32_bf16(urf, I0, a0a, 0, 0, 0);
      a1a = __builtin_amdgcn_mfma_f32_16x16x32_bf16(urf, I1, a1a, 0, 0, 0);
      a0a = __builtin_amdgcn_mfma_f32_16x16x32_bf16(ucf, I0, a0a, 0, 0, 0);
      a1a = __builtin_amdgcn_mfma_f32_16x16x32_bf16(ucf, I1, a1a, 0, 0, 0);
    }
#pragma unroll
    for (int eb = 0; eb < NEB; ++eb) {
      bf16x8 a;
      if (STAGE == 1) {
        a = ae;
      } else if (STAGE == 2) {
        if (eb == 0) a = ae;
        else {
          uint4 u = *(const uint4*)(ein1 + (size_t)p * 32 + 8 * g);
          u.x = relu_pk2(u.x); u.y = relu_pk2(u.y); u.z = relu_pk2(u.z); u.w = relu_pk2(u.w);
          a = u4_as_bf8(u);
        }
      } else {
        const __bf16* src = (eb == 0) ? ein1 : ein2;
        uint4 u = *(const uint4*)(src + (size_t)p * 32 + 8 * g);
        u.x = relu_pk2(u.x); u.y = relu_pk2(u.y); u.z = relu_pk2(u.z); u.w = relu_pk2(u.w);
        a = u4_as_bf8(u);
      }
      a0b = __builtin_amdgcn_mfma_f32_16x16x32_bf16(a, Bf[eb][0], a0b, 0, 0, 0);
      a1b = __builtin_amdgcn_mfma_f32_16x16x32_bf16(a, Bf[eb][1], a1b, 0, 0, 0);
    }
    f32x4 acc0 = a0a + a0b, acc1 = a1a + a1b;

    // h = relu(acc + b0) -> per-wave LDS tile [16][36] (transpose C->A)
#pragma unroll
    for (int r = 0; r < 4; ++r) {
      int m = 4 * g + r;
      hl[m * 36 + l15]      = fmaxf(acc0[r] + b0j0, 0.f);
      hl[m * 36 + l15 + 16] = fmaxf(acc1[r] + b0j1, 0.f);
    }
    f32x4 h0 = *(const f32x4*)&hl[l15 * 36 + 8 * g];
    f32x4 h1 = *(const f32x4*)&hl[l15 * 36 + 8 * g + 4];
    bf16x8 a2;
#pragma unroll
    for (int i = 0; i < 4; ++i) { a2[i] = (__bf16)h0[i]; a2[i + 4] = (__bf16)h1[i]; }
    f32x4 o0 = {0,0,0,0}, o1 = {0,0,0,0};
    o0 = __builtin_amdgcn_mfma_f32_16x16x32_bf16(a2, B2f[0], o0, 0, 0, 0);
    o1 = __builtin_amdgcn_mfma_f32_16x16x32_bf16(a2, B2f[1], o1, 0, 0, 0);

    if (STAGE <= 3) {
#pragma unroll
      for (int r = 0; r < 4; ++r) {
        int m = 4 * g + r;
        size_t eo = (size_t)(base + m) * 32;
        d1[eo + l15]      = (__bf16)(o0[r] + b1j0);
        d1[eo + l15 + 16] = (__bf16)(o1[r] + b1j1);
      }
    } else {
#pragma unroll
      for (int r = 0; r < 4; ++r) {
        int m = 4 * g + r;
        hl[m * 36 + l15]      = fmaxf(o0[r] + b1j0, 0.f);
        hl[m * 36 + l15 + 16] = fmaxf(o1[r] + b1j1, 0.f);
      }
      f32x4 q0 = *(const f32x4*)&hl[l15 * 36 + 8 * g];
      f32x4 q1 = *(const f32x4*)&hl[l15 * 36 + 8 * g + 4];
      bf16x8 a3;
#pragma unroll
      for (int i = 0; i < 4; ++i) { a3[i] = (__bf16)q0[i]; a3[i + 4] = (__bf16)q1[i]; }
      f32x4 ho = {0,0,0,0};
      ho = __builtin_amdgcn_mfma_f32_16x16x32_bf16(a3, Bh, ho, 0, 0, 0);
#pragma unroll
      for (int r = 0; r < 4; ++r) {
        int m = 4 * g + r;
        int po = base + m;
        float s = ho[r];
        float v = 0.f, sq = 0.f;
        if (l15 < 4) {
          v = s + bexc + eattr_s[(size_t)po * 4 + l15];
          sq = v * v;
        }
        sq += __shfl_xor(sq, 1);
        sq += __shfl_xor(sq, 2);
        if (l15 < 4) tmpEX[(size_t)po * 4 + l15] = v * (1.f / fmaxf(sqrtf(sq), 1e-12f));
        if (l15 == 4) tmpP[po] = 1.f / (1.f + __expf(-(s + bp)));
      }
    }
  }
}

// ---------------- unpermute outputs + beta copy (fused) ----------------
__global__ void unpermute_kernel(const int* __restrict__ inv,
                                 const float* __restrict__ tmpP,
                                 const float* __restrict__ tmpEX,
                                 const float* __restrict__ beta,
                                 float* __restrict__ outP, float* __restrict__ outEX,
                                 float* __restrict__ outB) {
  int e = blockIdx.x * blockDim.x + threadIdx.x;
  if (e >= EE) return;
  int p = inv[e];
  outP[e] = tmpP[p];
  float4 ex = *(const float4*)(tmpEX + (size_t)p * 4);
  *(float4*)(outEX + (size_t)e * 4) = ex;
  if (e < NN * 3) outB[e] = beta[e];
}

extern "C" void kernel_launch(void* const* d_in, const int* in_sizes, int n_in,
                              void* d_out, int out_size, void* d_ws, size_t ws_size,
                              hipStream_t stream) {
  const float* eattr = (const float*)d_in[2];
  const float* beta = (const float*)d_in[3];
  const float* w10 = (const float*)d_in[4];  const float* b10 = (const float*)d_in[5];
  const float* w11 = (const float*)d_in[6];  const float* b11 = (const float*)d_in[7];
  const float* w20 = (const float*)d_in[8];  const float* b20 = (const float*)d_in[9];
  const float* w21 = (const float*)d_in[10]; const float* b21 = (const float*)d_in[11];
  const float* w30 = (const float*)d_in[12]; const float* b30 = (const float*)d_in[13];
  const float* w31 = (const float*)d_in[14]; const float* b31 = (const float*)d_in[15];
  const float* w40 = (const float*)d_in[16]; const float* b40 = (const float*)d_in[17];
  const float* w41 = (const float*)d_in[18]; const float* b41 = (const float*)d_in[19];
  const float* wl01 = (const float*)d_in[20]; const float* bl01 = (const float*)d_in[21];
  const float* wl02 = (const float*)d_in[22]; const float* bl02 = (const float*)d_in[23];
  const float* wl1 = (const float*)d_in[24];  const float* bl1 = (const float*)d_in[25];
  const float* wl2 = (const float*)d_in[26];  const float* bl2 = (const float*)d_in[27];
  const int* rowi = (const int*)d_in[1];
  const int* coli = rowi + EE;

  char* w = (char*)d_ws;
  auto alloc = [&](size_t bytes) {
    char* p = w;
    w += (bytes + 255) & ~(size_t)255;
    return p;
  };
  __bf16* e1b = (__bf16*)alloc((size_t)EE * 32 * 2);  // pre-relu, sorted order
  __bf16* e2b = (__bf16*)alloc((size_t)EE * 32 * 2);
  __bf16* e3b = (__bf16*)alloc((size_t)EE * 32 * 2);
  __bf16* ub  = (__bf16*)alloc((size_t)NN * 64 * 2);  // per-stage node proj (reused)
  __bf16* x21 = (__bf16*)alloc((size_t)NN * 64 * 2);  // [x2 | x1]
  __bf16* x32 = (__bf16*)alloc((size_t)NN * 64 * 2);  // [x3 | x2]
  int* deg = (int*)alloc(NN * 4);
  int* offs = (int*)alloc((NN + 1) * 4);
  int* cursor = (int*)alloc(NN * 4);
  int* rows_s = (int*)alloc(EE * 4);
  int* cols_s = (int*)alloc(EE * 4);
  int* inv = (int*)alloc(EE * 4);
  __bf16* ebf = (__bf16*)alloc((size_t)EE * 4 * 2);   // sorted bf16 edge_attr
  float* eattr_s = (float*)alloc((size_t)EE * 4 * 4); // sorted fp32 edge_attr
  float* tmpP = (float*)alloc((size_t)EE * 4);
  float* tmpEX = (float*)alloc((size_t)EE * 4 * 4);
  float* headw = (float*)alloc(256 * 4);
  int* partial = (int*)alloc(64 * 4);
  __bf16* packw = (__bf16*)alloc((size_t)43 * 512 * 2);

  float* outP = (float*)d_out;
  float* outEX = outP + EE;
  float* outB = outP + (size_t)5 * EE;

  __bf16* pk1 = packw;
  __bf16* pk2 = packw + 4 * 512;
  __bf16* pk3 = packw + 14 * 512;
  __bf16* pk4 = packw + 28 * 512;

  init_kernel<<<(NN + 255) / 256, 256, 0, stream>>>(deg, bl01, bl02, wl1, bl1, wl2, bl2, headw);
  pack_all_kernel<<<43, 256, 0, stream>>>(w10, w11, w20, w21, w30, w31, w40, w41,
                                          wl01, wl1, wl02, wl2, packw);
  hist_kernel<<<(EE + 255) / 256, 256, 0, stream>>>(rowi, deg);
  scanA_kernel<<<SCAN_NBLK, 1024, 0, stream>>>(deg, offs, partial);
  scanB_kernel<<<SCAN_NBLK, 1024, 0, stream>>>(partial, offs, cursor);
  scatter_kernel<<<(EE + 255) / 256, 256, 0, stream>>>(rowi, coli, eattr, cursor,
                                                       rows_s, cols_s, ebf, eattr_s, inv);

  conv_kernel<1><<<2048, 256, 0, stream>>>(pk1, b10, b11, rows_s, cols_s, ebf,
                                           (const __bf16*)nullptr, (const __bf16*)nullptr,
                                           (const __bf16*)nullptr, e1b,
                                           (const float*)nullptr, (const float*)nullptr,
                                           (float*)nullptr, (float*)nullptr);
  agg_kernel<<<(NN * 32 + 255) / 256, 256, 0, stream>>>(e1b, offs, x21, 64, 32,
                                                        (__bf16*)nullptr, 0, 0);
  nodeproj_kernel<32><<<(NPTILES + 3) / 4, 256, 0, stream>>>(pk2, x21, 32, 64, ub);
  conv_kernel<2><<<2048, 256, 0, stream>>>(pk2, b20, b21, rows_s, cols_s, ebf,
                                           ub, e1b, (const __bf16*)nullptr, e2b,
                                           (const float*)nullptr, (const float*)nullptr,
                                           (float*)nullptr, (float*)nullptr);
  agg_kernel<<<(NN * 32 + 255) / 256, 256, 0, stream>>>(e2b, offs, x21, 64, 0, x32, 64, 32);
  nodeproj_kernel<64><<<(NPTILES + 3) / 4, 256, 0, stream>>>(pk3, x21, 0, 64, ub);
  conv_kernel<3><<<2048, 256, 0, stream>>>(pk3, b30, b31, rows_s, cols_s, ebf,
                                           ub, e2b, e1b, e3b,
                                           (const float*)nullptr, (const float*)nullptr,
                                           (float*)nullptr, (float*)nullptr);
  agg_kernel<<<(NN * 32 + 255) / 256, 256, 0, stream>>>(e3b, offs, x32, 64, 0,
                                                        (__bf16*)nullptr, 0, 0);
  nodeproj_kernel<64><<<(NPTILES + 3) / 4, 256, 0, stream>>>(pk4, x32, 0, 64, ub);
  conv_kernel<4><<<2048, 256, 0, stream>>>(pk4, b40, b41, rows_s, cols_s, ebf,
                                           ub, e3b, e2b, (__bf16*)nullptr,
                                           eattr_s, headw, tmpP, tmpEX);
  unpermute_kernel<<<(EE + 255) / 256, 256, 0, stream>>>(inv, tmpP, tmpEX, beta,
                                                         outP, outEX, outB);
}